// Round 8
// baseline (97.217 us; speedup 1.0000x reference)
//
#include <hip/hip_runtime.h>
#include <hip/hip_bf16.h>

#define NB 4
#define NC 256
#define NN 4096
#define NCR 32
#define PITCH2 136  // shorts/row; read units (lm*17+4nch+lg) mod 8 uniform -> min cycles

typedef __attribute__((ext_vector_type(8))) short short8_t;
typedef __attribute__((ext_vector_type(4))) float f32x4;
typedef __attribute__((ext_vector_type(2))) int int2_t;
typedef __attribute__((ext_vector_type(4))) int int4_t;
typedef __attribute__((ext_vector_type(4))) float float4_t;

static __device__ __forceinline__ unsigned short f2bf(float f) {
  unsigned u = __builtin_bit_cast(unsigned, f);
  u += 0x7FFFu + ((u >> 16) & 1u);
  return (unsigned short)(u >> 16);
}

static __device__ __forceinline__ unsigned cvt_pk(float lo, float hi) {
  unsigned r;
  asm("v_cvt_pk_bf16_f32 %0, %1, %2" : "=v"(r) : "v"(lo), "v"(hi));
  return r;
}

// LDS-only barrier: drains lgkmcnt but leaves global loads in flight.
static __device__ __forceinline__ void lds_barrier() {
  asm volatile("s_waitcnt lgkmcnt(0)\n\ts_barrier" ::: "memory");
}

// ---------------------------------------------------------------------------
// Kernel 0: one-time W pack f32 -> bf16. rows [0,32)=Wq, [32,64)=Wk, [64,320)=Wv
// ---------------------------------------------------------------------------
__global__ __launch_bounds__(64) void pack_w_kernel(
    const float* __restrict__ Wq, const float* __restrict__ Wk,
    const float* __restrict__ Wv, unsigned short* __restrict__ Wbf)
{
  const int row = blockIdx.x;
  const int t = threadIdx.x;
  const float* src = row < 32 ? Wq + (size_t)row * NC
                   : (row < 64 ? Wk + (size_t)(row - 32) * NC
                               : Wv + (size_t)(row - 64) * NC);
  float4_t v = *(const float4_t*)(src + t * 4);
  int2_t p;
  p[0] = cvt_pk(v[0], v[1]);
  p[1] = cvt_pk(v[2], v[3]);
  *(int2_t*)(Wbf + (size_t)row * NC + t * 4) = p;
}

// ---------------------------------------------------------------------------
// Kernel 1: QKV projection. BM=32, grid 512, 2 blocks/CU. x chunk staged in
// LDS bf16, XOR-swizzled. Swapped MFMA: D^T[m][d]; V stores b64 along n.
// ---------------------------------------------------------------------------
__global__ __launch_bounds__(256, 2) void qkv_kernel(
    const float* __restrict__ x, const unsigned short* __restrict__ Wbf,
    const float* __restrict__ bq, const float* __restrict__ bk,
    const float* __restrict__ bv,
    unsigned short* __restrict__ Qt, unsigned short* __restrict__ Kt,
    unsigned short* __restrict__ Vt)
{
  __shared__ unsigned short xT[2][32 * 64];

  const int bid = blockIdx.x;
  const int b   = bid >> 7;
  const int m0  = (bid & 127) * 32;
  const int tid = threadIdx.x;
  const int w    = tid >> 6;
  const int lane = tid & 63;
  const int lg   = lane >> 4;
  const int lm   = lane & 15;

  const int mcol = tid & 31, kg = tid >> 5;
  const float* xld = x + (size_t)b * NC * NN + (size_t)(kg * 8) * NN + m0 + mcol;
  const int wofs = mcol * 64 + ((kg ^ (mcol & 7)) << 3);
  const unsigned short* wrow = Wbf + (size_t)(w * 80 + lm) * NC;

  const f32x4 zero4 = {0.f, 0.f, 0.f, 0.f};
  f32x4 acc[5][2];
#pragma unroll
  for (int df = 0; df < 5; df++)
#pragma unroll
    for (int mf = 0; mf < 2; mf++) acc[df][mf] = zero4;

  float xg[8], xn[8];
#pragma unroll
  for (int j = 0; j < 8; j++) xg[j] = xld[(size_t)j * NN];

#define QCHUNK(C, XC, XN, BUF) {                                              \
    if ((C) < 3) {                                                            \
      _Pragma("unroll") for (int j = 0; j < 8; j++)                           \
        XN[j] = xld[(size_t)(((C) + 1) * 64 + j) * NN];                       \
    }                                                                         \
    int4_t xwv;                                                               \
    xwv[0] = cvt_pk(XC[0], XC[1]); xwv[1] = cvt_pk(XC[2], XC[3]);             \
    xwv[2] = cvt_pk(XC[4], XC[5]); xwv[3] = cvt_pk(XC[6], XC[7]);             \
    *(int4_t*)(&xT[BUF][wofs]) = xwv;                                         \
    __syncthreads();                                                          \
    _Pragma("unroll") for (int ks = 0; ks < 2; ks++) {                        \
      short8_t xf[2];                                                         \
      _Pragma("unroll") for (int mf = 0; mf < 2; mf++) {                      \
        const int row = mf * 16 + lm;                                         \
        const int unit = (ks * 4 + lg) ^ (lm & 7);                            \
        xf[mf] = *(const short8_t*)(&xT[BUF][row * 64 + unit * 8]);           \
      }                                                                       \
      _Pragma("unroll") for (int df = 0; df < 5; df++) {                      \
        const short8_t wf = *(const short8_t*)(wrow + (size_t)df * 16 * NC +  \
                                               (C) * 64 + ks * 32 + lg * 8);  \
        _Pragma("unroll") for (int mf = 0; mf < 2; mf++)                      \
          acc[df][mf] = __builtin_amdgcn_mfma_f32_16x16x32_bf16(              \
              xf[mf], wf, acc[df][mf], 0, 0, 0);                              \
      }                                                                       \
    }                                                                         \
  }

  QCHUNK(0, xg, xn, 0)
  QCHUNK(1, xn, xg, 1)
  QCHUNK(2, xg, xn, 0)
  QCHUNK(3, xn, xg, 1)
#undef QCHUNK

#pragma unroll
  for (int df = 0; df < 5; df++) {
    const int dbase = w * 80 + df * 16;
    if (dbase < 64) {
      const bool isq = dbase < 32;
      const float bia = isq ? bq[dbase + lm] : bk[dbase - 32 + lm];
      unsigned short* dst = isq ? Qt : Kt;
      const int dcol = (isq ? dbase : dbase - 32) + lm;
#pragma unroll
      for (int mf = 0; mf < 2; mf++)
#pragma unroll
        for (int i = 0; i < 4; i++) {
          const int m = m0 + mf * 16 + lg * 4 + i;
          dst[((size_t)b * NN + m) * NCR + dcol] = f2bf(acc[df][mf][i] + bia);
        }
    } else {
      const int c = dbase - 64 + lm;
      const float bia = bv[c];
#pragma unroll
      for (int mf = 0; mf < 2; mf++) {
        int2_t p;
        p[0] = cvt_pk(acc[df][mf][0] + bia, acc[df][mf][1] + bia);
        p[1] = cvt_pk(acc[df][mf][2] + bia, acc[df][mf][3] + bia);
        *(int2_t*)(Vt + ((size_t)b * NC + c) * NN + m0 + mf * 16 + lg * 4) = p;
      }
    }
  }
}

// ---------------------------------------------------------------------------
// Kernel 2: streaming attention, n-tile 128/iter (32 iters). S pipelined one
// tile ahead: iter t computes S[t+1] while PV consumes S[t]. One lgkm-only
// barrier per iter. Grid 512 = batch x c-half x m-tile(64), 4 waves, 2 blk/CU.
// Wave w: S rows {16w, 64+16w}+[0,16); PV c-rows ch*128 + w*32 + [0,32).
// ---------------------------------------------------------------------------
__global__ __launch_bounds__(256, 2) void attn_kernel(
    const unsigned short* __restrict__ Qt, const unsigned short* __restrict__ Kt,
    const unsigned short* __restrict__ Vt, const float* __restrict__ x,
    const float* __restrict__ gamma, float* __restrict__ out)
{
  __shared__ unsigned short Slds[2][64 * PITCH2];  // 34.8 KB
  __shared__ float dlds[4][64];

  const int bid = blockIdx.x;
  const int xcd = bid & 7;
  const int b   = xcd >> 1;
  const int ch  = xcd & 1;
  const int m0  = (bid >> 3) * 64;
  const int tid = threadIdx.x;
  const int w    = tid >> 6;
  const int lane = tid & 63;
  const int lg   = lane >> 4;
  const int lm   = lane & 15;

  const unsigned short* Qb = Qt + (size_t)b * NN * NCR;
  const unsigned short* Kp = Kt + (size_t)b * NN * NCR +
                             (size_t)(w * 16 + lm) * NCR + lg * 8;
  const unsigned short* pV[2];
#pragma unroll
  for (int cf = 0; cf < 2; cf++)
    pV[cf] = Vt + ((size_t)b * NC + ch * 128 + w * 32 + cf * 16 + lm) * NN + lg * 8;

  short8_t qf[4];
#pragma unroll
  for (int mf = 0; mf < 4; mf++)
    qf[mf] = *(const short8_t*)(Qb + (size_t)(m0 + mf * 16 + lm) * NCR + lg * 8);

  const f32x4 zero4 = {0.f, 0.f, 0.f, 0.f};
  f32x4 acc[2][4];
#pragma unroll
  for (int cf = 0; cf < 2; cf++)
#pragma unroll
    for (int mf = 0; mf < 4; mf++) acc[cf][mf] = zero4;
  float dsum[4] = {0.f, 0.f, 0.f, 0.f};

  // S-compute for one 64-n subtile (rows w*16+[0,16)) into buffer WB at NSOFF
#define SCOMP(KREG, WB, NSOFF) {                                              \
    _Pragma("unroll") for (int mf = 0; mf < 4; mf++) {                        \
      f32x4 s = __builtin_amdgcn_mfma_f32_16x16x32_bf16(KREG, qf[mf], zero4, 0, 0, 0); \
      float s0 = fmaxf(s[0], 0.f), s1 = fmaxf(s[1], 0.f);                     \
      float s2 = fmaxf(s[2], 0.f), s3 = fmaxf(s[3], 0.f);                     \
      dsum[mf] += (s0 + s1) + (s2 + s3);                                      \
      int2_t p; p[0] = cvt_pk(s0, s1); p[1] = cvt_pk(s2, s3);                 \
      *(int2_t*)(&Slds[WB][(mf * 16 + lm) * PITCH2 + (NSOFF) + w * 16 + lg * 4]) = p; \
    }                                                                         \
  }

  // prologue: S[0] into buf0; load K[1] frag pair
  short8_t kA0, kA1, kB0, kB1;
  {
    const short8_t k00 = *(const short8_t*)(Kp);
    const short8_t k01 = *(const short8_t*)(Kp + (size_t)64 * NCR);
    SCOMP(k00, 0, 0)
    SCOMP(k01, 0, 64)
  }
  kA0 = *(const short8_t*)(Kp + (size_t)128 * NCR);
  kA1 = *(const short8_t*)(Kp + (size_t)192 * NCR);
  lds_barrier();

  // ITER(T): V[T] issue-early; load K[T+2]; compute S[T+1]; PV with S[T].
#define ITER(T, KC0, KC1, KN0, KN1, WB, RB, DOS) {                            \
    const int nv = (T) * 128;                                                 \
    short8_t vc[2][4];                                                        \
    _Pragma("unroll") for (int cf = 0; cf < 2; cf++)                          \
      _Pragma("unroll") for (int nch = 0; nch < 4; nch++)                     \
        vc[cf][nch] = *(const short8_t*)(pV[cf] + nv + nch * 32);             \
    const int nk = (((T) + 2) & 31) * 128;                                    \
    KN0 = *(const short8_t*)(Kp + (size_t)nk * NCR);                          \
    KN1 = *(const short8_t*)(Kp + (size_t)(nk + 64) * NCR);                   \
    if (DOS) { SCOMP(KC0, WB, 0) SCOMP(KC1, WB, 64) }                         \
    _Pragma("unroll") for (int nch = 0; nch < 4; nch++) {                     \
      short8_t sf[4];                                                         \
      _Pragma("unroll") for (int mf = 0; mf < 4; mf++)                        \
        sf[mf] = *(const short8_t*)(&Slds[RB][(mf * 16 + lm) * PITCH2 +       \
                                             nch * 32 + lg * 8]);             \
      _Pragma("unroll") for (int cf = 0; cf < 2; cf++)                        \
        _Pragma("unroll") for (int mf = 0; mf < 4; mf++)                      \
          acc[cf][mf] = __builtin_amdgcn_mfma_f32_16x16x32_bf16(              \
              vc[cf][nch], sf[mf], acc[cf][mf], 0, 0, 0);                     \
    }                                                                         \
    lds_barrier();                                                            \
  }

#pragma unroll 1
  for (int t = 0; t < 30; t += 2) {
    ITER(t, kA0, kA1, kB0, kB1, 1, 0, true)
    ITER(t + 1, kB0, kB1, kA0, kA1, 0, 1, true)
  }
  ITER(30, kA0, kA1, kB0, kB1, 1, 0, true)
  ITER(31, kB0, kB1, kA0, kA1, 0, 1, false)
#undef ITER
#undef SCOMP

  // denominator: fold lane groups, then 4 waves via LDS
#pragma unroll
  for (int mf = 0; mf < 4; mf++) {
    float v = dsum[mf];
    v += __shfl_xor(v, 16);
    v += __shfl_xor(v, 32);
    if (lane < 16) dlds[w][mf * 16 + lane] = v;
  }
  __syncthreads();

  const float g0 = gamma[0];
  float rden[4];
#pragma unroll
  for (int mf = 0; mf < 4; mf++) {
    const int mloc = mf * 16 + lm;
    float den = dlds[0][mloc] + dlds[1][mloc] + dlds[2][mloc] + dlds[3][mloc];
    den = den > 1e-12f ? den : 1e-12f;
    rden[mf] = 1.0f / den;
  }

  const float* xb = x + (size_t)b * NC * NN;
  float* ob = out + (size_t)b * NC * NN;
#pragma unroll
  for (int cf = 0; cf < 2; cf++) {
#pragma unroll
    for (int i = 0; i < 4; i++) {
      const int c = ch * 128 + w * 32 + cf * 16 + lg * 4 + i;
#pragma unroll
      for (int mf = 0; mf < 4; mf++) {
        const int m = m0 + mf * 16 + lm;
        ob[(size_t)c * NN + m] = g0 * acc[cf][mf][i] * rden[mf] + xb[(size_t)c * NN + m];
      }
    }
  }
}

extern "C" void kernel_launch(void* const* d_in, const int* in_sizes, int n_in,
                              void* d_out, int out_size, void* d_ws, size_t ws_size,
                              hipStream_t stream) {
  const float* x     = (const float*)d_in[0];
  const float* Wq    = (const float*)d_in[1];
  const float* bq    = (const float*)d_in[2];
  const float* Wk    = (const float*)d_in[3];
  const float* bk    = (const float*)d_in[4];
  const float* Wv    = (const float*)d_in[5];
  const float* bv    = (const float*)d_in[6];
  const float* gamma = (const float*)d_in[7];
  float* out = (float*)d_out;

  unsigned short* Wbf = (unsigned short*)d_ws;
  unsigned short* Qt  = Wbf + (size_t)320 * NC;
  unsigned short* Kt  = Qt + (size_t)NB * NN * NCR;
  unsigned short* Vt  = Kt + (size_t)NB * NN * NCR;

  hipLaunchKernelGGL(pack_w_kernel, dim3(320), dim3(64), 0, stream,
                     Wq, Wk, Wv, Wbf);
  hipLaunchKernelGGL(qkv_kernel, dim3(512), dim3(256), 0, stream,
                     x, Wbf, bq, bk, bv, Qt, Kt, Vt);
  hipLaunchKernelGGL(attn_kernel, dim3(512), dim3(256), 0, stream,
                     Qt, Kt, Vt, x, gamma, out);
}

// Round 9
// 92.830 us; speedup vs baseline: 1.0473x; 1.0473x over previous
//
#include <hip/hip_runtime.h>
#include <hip/hip_bf16.h>

#define NB 4
#define NC 256
#define NN 4096
#define NCR 32
#define PITCH 72          // S LDS pitch (shorts)
#define VP (NN + 32)      // V row pitch in shorts: 8256 B = 129 cache lines (channel spread)

typedef __attribute__((ext_vector_type(8))) short short8_t;
typedef __attribute__((ext_vector_type(4))) float f32x4;
typedef __attribute__((ext_vector_type(2))) int int2_t;
typedef __attribute__((ext_vector_type(4))) int int4_t;
typedef __attribute__((ext_vector_type(4))) float float4_t;

static __device__ __forceinline__ unsigned short f2bf(float f) {
  unsigned u = __builtin_bit_cast(unsigned, f);
  u += 0x7FFFu + ((u >> 16) & 1u);
  return (unsigned short)(u >> 16);
}

static __device__ __forceinline__ unsigned cvt_pk(float lo, float hi) {
  unsigned r;
  asm("v_cvt_pk_bf16_f32 %0, %1, %2" : "=v"(r) : "v"(lo), "v"(hi));
  return r;
}

// LDS-only barrier: drains lgkmcnt but leaves global loads in flight.
static __device__ __forceinline__ void lds_barrier() {
  asm volatile("s_waitcnt lgkmcnt(0)\n\ts_barrier" ::: "memory");
}

// ---------------------------------------------------------------------------
// Kernel 0: one-time W pack f32 -> bf16. rows [0,32)=Wq, [32,64)=Wk, [64,320)=Wv
// ---------------------------------------------------------------------------
__global__ __launch_bounds__(64) void pack_w_kernel(
    const float* __restrict__ Wq, const float* __restrict__ Wk,
    const float* __restrict__ Wv, unsigned short* __restrict__ Wbf)
{
  const int row = blockIdx.x;
  const int t = threadIdx.x;
  const float* src = row < 32 ? Wq + (size_t)row * NC
                   : (row < 64 ? Wk + (size_t)(row - 32) * NC
                               : Wv + (size_t)(row - 64) * NC);
  float4_t v = *(const float4_t*)(src + t * 4);
  int2_t p;
  p[0] = cvt_pk(v[0], v[1]);
  p[1] = cvt_pk(v[2], v[3]);
  *(int2_t*)(Wbf + (size_t)row * NC + t * 4) = p;
}

// ---------------------------------------------------------------------------
// Kernel 1: QKV projection. BM=32, grid 512, 2 blocks/CU. x chunk staged in
// LDS bf16, XOR-swizzled. Swapped MFMA: D^T[m][d]; V stores b64 along n
// into the PITCHED Vt layout (row pitch VP shorts).
// ---------------------------------------------------------------------------
__global__ __launch_bounds__(256, 2) void qkv_kernel(
    const float* __restrict__ x, const unsigned short* __restrict__ Wbf,
    const float* __restrict__ bq, const float* __restrict__ bk,
    const float* __restrict__ bv,
    unsigned short* __restrict__ Qt, unsigned short* __restrict__ Kt,
    unsigned short* __restrict__ Vt)
{
  __shared__ unsigned short xT[2][32 * 64];

  const int bid = blockIdx.x;
  const int b   = bid >> 7;
  const int m0  = (bid & 127) * 32;
  const int tid = threadIdx.x;
  const int w    = tid >> 6;
  const int lane = tid & 63;
  const int lg   = lane >> 4;
  const int lm   = lane & 15;

  const int mcol = tid & 31, kg = tid >> 5;
  const float* xld = x + (size_t)b * NC * NN + (size_t)(kg * 8) * NN + m0 + mcol;
  const int wofs = mcol * 64 + ((kg ^ (mcol & 7)) << 3);
  const unsigned short* wrow = Wbf + (size_t)(w * 80 + lm) * NC;

  const f32x4 zero4 = {0.f, 0.f, 0.f, 0.f};
  f32x4 acc[5][2];
#pragma unroll
  for (int df = 0; df < 5; df++)
#pragma unroll
    for (int mf = 0; mf < 2; mf++) acc[df][mf] = zero4;

  float xg[8], xn[8];
#pragma unroll
  for (int j = 0; j < 8; j++) xg[j] = xld[(size_t)j * NN];

#define QCHUNK(C, XC, XN, BUF) {                                              \
    if ((C) < 3) {                                                            \
      _Pragma("unroll") for (int j = 0; j < 8; j++)                           \
        XN[j] = xld[(size_t)(((C) + 1) * 64 + j) * NN];                       \
    }                                                                         \
    int4_t xwv;                                                               \
    xwv[0] = cvt_pk(XC[0], XC[1]); xwv[1] = cvt_pk(XC[2], XC[3]);             \
    xwv[2] = cvt_pk(XC[4], XC[5]); xwv[3] = cvt_pk(XC[6], XC[7]);             \
    *(int4_t*)(&xT[BUF][wofs]) = xwv;                                         \
    __syncthreads();                                                          \
    _Pragma("unroll") for (int ks = 0; ks < 2; ks++) {                        \
      short8_t xf[2];                                                         \
      _Pragma("unroll") for (int mf = 0; mf < 2; mf++) {                      \
        const int row = mf * 16 + lm;                                         \
        const int unit = (ks * 4 + lg) ^ (lm & 7);                            \
        xf[mf] = *(const short8_t*)(&xT[BUF][row * 64 + unit * 8]);           \
      }                                                                       \
      _Pragma("unroll") for (int df = 0; df < 5; df++) {                      \
        const short8_t wf = *(const short8_t*)(wrow + (size_t)df * 16 * NC +  \
                                               (C) * 64 + ks * 32 + lg * 8);  \
        _Pragma("unroll") for (int mf = 0; mf < 2; mf++)                      \
          acc[df][mf] = __builtin_amdgcn_mfma_f32_16x16x32_bf16(              \
              xf[mf], wf, acc[df][mf], 0, 0, 0);                              \
      }                                                                       \
    }                                                                         \
  }

  QCHUNK(0, xg, xn, 0)
  QCHUNK(1, xn, xg, 1)
  QCHUNK(2, xg, xn, 0)
  QCHUNK(3, xn, xg, 1)
#undef QCHUNK

#pragma unroll
  for (int df = 0; df < 5; df++) {
    const int dbase = w * 80 + df * 16;
    if (dbase < 64) {
      const bool isq = dbase < 32;
      const float bia = isq ? bq[dbase + lm] : bk[dbase - 32 + lm];
      unsigned short* dst = isq ? Qt : Kt;
      const int dcol = (isq ? dbase : dbase - 32) + lm;
#pragma unroll
      for (int mf = 0; mf < 2; mf++)
#pragma unroll
        for (int i = 0; i < 4; i++) {
          const int m = m0 + mf * 16 + lg * 4 + i;
          dst[((size_t)b * NN + m) * NCR + dcol] = f2bf(acc[df][mf][i] + bia);
        }
    } else {
      const int c = dbase - 64 + lm;
      const float bia = bv[c];
#pragma unroll
      for (int mf = 0; mf < 2; mf++) {
        int2_t p;
        p[0] = cvt_pk(acc[df][mf][0] + bia, acc[df][mf][1] + bia);
        p[1] = cvt_pk(acc[df][mf][2] + bia, acc[df][mf][3] + bia);
        *(int2_t*)(Vt + (size_t)(b * NC + c) * VP + m0 + mf * 16 + lg * 4) = p;
      }
    }
  }
}

// ---------------------------------------------------------------------------
// Kernel 2: streaming attention, M-TILE 128 (halves V L2 traffic).
// Grid 512 = batch(4) x c-quarter(4) x m-tile(32), 4 waves, 2 blocks/CU.
// Wave w: S rows [16w,16w+16) for all 128 m; PV c-rows cq*64 + w*16 + [0,16).
// S pipelined one tile ahead; one lgkm-only barrier/iter; V row pitch VP
// breaks the 8KB power-of-2 L2 channel aliasing.
// ---------------------------------------------------------------------------
__global__ __launch_bounds__(256, 2) void attn_kernel(
    const unsigned short* __restrict__ Qt, const unsigned short* __restrict__ Kt,
    const unsigned short* __restrict__ Vt, const float* __restrict__ x,
    const float* __restrict__ gamma, float* __restrict__ out)
{
  __shared__ unsigned short Slds[2][128 * PITCH];  // 36.9 KB
  __shared__ float dlds[4][128];                   // 2 KB

  const int bid = blockIdx.x;
  const int xcd = bid & 7;
  const int idx = bid >> 3;              // 0..63
  const int b   = xcd >> 1;              // batch per XCD pair
  const int cq  = (xcd & 1) * 2 + (idx & 1);  // c-quarter 0..3 (64 rows)
  const int mt  = idx >> 1;              // 0..31
  const int m0  = mt * 128;
  const int cbase = cq * 64;
  const int tid = threadIdx.x;
  const int w    = tid >> 6;
  const int lane = tid & 63;
  const int lg   = lane >> 4;
  const int lm   = lane & 15;

  const unsigned short* Qb = Qt + (size_t)b * NN * NCR;
  const unsigned short* Kp = Kt + (size_t)b * NN * NCR +
                             (size_t)(w * 16 + lm) * NCR + lg * 8;
  const unsigned short* pV = Vt + (size_t)(b * NC + cbase + w * 16 + lm) * VP + lg * 8;

  short8_t qf[8];
#pragma unroll
  for (int mf = 0; mf < 8; mf++)
    qf[mf] = *(const short8_t*)(Qb + (size_t)(m0 + mf * 16 + lm) * NCR + lg * 8);

  const f32x4 zero4 = {0.f, 0.f, 0.f, 0.f};
  f32x4 acc[8];
#pragma unroll
  for (int mf = 0; mf < 8; mf++) acc[mf] = zero4;
  float dsum[8] = {0.f, 0.f, 0.f, 0.f, 0.f, 0.f, 0.f, 0.f};

  const int swofs = w * 16 + lg * 4;

  // S-compute for one 64-n tile into LDS buffer WB
#define SCOMP(KREG, WB) {                                                     \
    _Pragma("unroll") for (int mf = 0; mf < 8; mf++) {                        \
      f32x4 s = __builtin_amdgcn_mfma_f32_16x16x32_bf16(KREG, qf[mf], zero4, 0, 0, 0); \
      float s0 = fmaxf(s[0], 0.f), s1 = fmaxf(s[1], 0.f);                     \
      float s2 = fmaxf(s[2], 0.f), s3 = fmaxf(s[3], 0.f);                     \
      dsum[mf] += (s0 + s1) + (s2 + s3);                                      \
      int2_t p; p[0] = cvt_pk(s0, s1); p[1] = cvt_pk(s2, s3);                 \
      *(int2_t*)(&Slds[WB][(mf * 16 + lm) * PITCH + swofs]) = p;              \
    }                                                                         \
  }

  // prologue: S[0] into buf0; preload K[1] and V[0]
  short8_t kA, kB, vA[2], vB[2];
  {
    const short8_t k0 = *(const short8_t*)(Kp);
    SCOMP(k0, 0)
  }
  kA = *(const short8_t*)(Kp + (size_t)64 * NCR);
  vA[0] = *(const short8_t*)(pV);
  vA[1] = *(const short8_t*)(pV + 32);
  lds_barrier();

  // ITER(T): load K[T+2], V[T+1]; compute S[T+1] -> WB; PV S[T] (RB) with V[T].
#define ITER(T, KU, KF, VU, VF, WB, RB, DOS) {                                \
    const int nk = (((T) + 2) & 63) * 64;                                     \
    KF = *(const short8_t*)(Kp + (size_t)nk * NCR);                           \
    const int nv = (((T) + 1) & 63) * 64;                                     \
    VF[0] = *(const short8_t*)(pV + nv);                                      \
    VF[1] = *(const short8_t*)(pV + nv + 32);                                 \
    if (DOS) { SCOMP(KU, WB) }                                                \
    _Pragma("unroll") for (int nch = 0; nch < 2; nch++) {                     \
      short8_t sf[8];                                                         \
      _Pragma("unroll") for (int mf = 0; mf < 8; mf++)                        \
        sf[mf] = *(const short8_t*)(&Slds[RB][(mf * 16 + lm) * PITCH +        \
                                             nch * 32 + lg * 8]);             \
      _Pragma("unroll") for (int mf = 0; mf < 8; mf++)                        \
        acc[mf] = __builtin_amdgcn_mfma_f32_16x16x32_bf16(                    \
            VU[nch], sf[mf], acc[mf], 0, 0, 0);                               \
    }                                                                         \
    lds_barrier();                                                            \
  }

#pragma unroll 1
  for (int t = 0; t < 62; t += 2) {
    ITER(t, kA, kB, vA, vB, 1, 0, true)
    ITER(t + 1, kB, kA, vB, vA, 0, 1, true)
  }
  ITER(62, kA, kB, vA, vB, 1, 0, true)
  ITER(63, kB, kA, vB, vA, 0, 1, false)
#undef ITER
#undef SCOMP

  // denominator: fold lane groups (lg), then 4 waves via LDS
#pragma unroll
  for (int mf = 0; mf < 8; mf++) {
    float v = dsum[mf];
    v += __shfl_xor(v, 16);
    v += __shfl_xor(v, 32);
    if (lane < 16) dlds[w][mf * 16 + lane] = v;
  }
  __syncthreads();

  const float g0 = gamma[0];
  float rden[8];
#pragma unroll
  for (int mf = 0; mf < 8; mf++) {
    const int mloc = mf * 16 + lm;
    float den = dlds[0][mloc] + dlds[1][mloc] + dlds[2][mloc] + dlds[3][mloc];
    den = den > 1e-12f ? den : 1e-12f;
    rden[mf] = 1.0f / den;
  }

  const float* xb = x + (size_t)b * NC * NN;
  float* ob = out + (size_t)b * NC * NN;
#pragma unroll
  for (int i = 0; i < 4; i++) {
    const int c = cbase + w * 16 + lg * 4 + i;
#pragma unroll
    for (int mf = 0; mf < 8; mf++) {
      const int m = m0 + mf * 16 + lm;
      ob[(size_t)c * NN + m] = g0 * acc[mf][i] * rden[mf] + xb[(size_t)c * NN + m];
    }
  }
}

extern "C" void kernel_launch(void* const* d_in, const int* in_sizes, int n_in,
                              void* d_out, int out_size, void* d_ws, size_t ws_size,
                              hipStream_t stream) {
  const float* x     = (const float*)d_in[0];
  const float* Wq    = (const float*)d_in[1];
  const float* bq    = (const float*)d_in[2];
  const float* Wk    = (const float*)d_in[3];
  const float* bk    = (const float*)d_in[4];
  const float* Wv    = (const float*)d_in[5];
  const float* bv    = (const float*)d_in[6];
  const float* gamma = (const float*)d_in[7];
  float* out = (float*)d_out;

  // ws (bf16): Wbf[320][256], Qt[4][4096][32], Kt[4][4096][32], Vt[4][256][VP]
  unsigned short* Wbf = (unsigned short*)d_ws;
  unsigned short* Qt  = Wbf + (size_t)320 * NC;
  unsigned short* Kt  = Qt + (size_t)NB * NN * NCR;
  unsigned short* Vt  = Kt + (size_t)NB * NN * NCR;

  hipLaunchKernelGGL(pack_w_kernel, dim3(320), dim3(64), 0, stream,
                     Wq, Wk, Wv, Wbf);
  hipLaunchKernelGGL(qkv_kernel, dim3(512), dim3(256), 0, stream,
                     x, Wbf, bq, bk, bv, Qt, Kt, Vt);
  hipLaunchKernelGGL(attn_kernel, dim3(512), dim3(256), 0, stream,
                     Qt, Kt, Vt, x, gamma, out);
}

// Round 10
// 90.663 us; speedup vs baseline: 1.0723x; 1.0239x over previous
//
#include <hip/hip_runtime.h>
#include <hip/hip_bf16.h>

#define NB 4
#define NC 256
#define NN 4096
#define NCR 32

typedef __attribute__((ext_vector_type(8))) short short8_t;
typedef __attribute__((ext_vector_type(4))) float f32x4;
typedef __attribute__((ext_vector_type(16))) float f32x16;
typedef __attribute__((ext_vector_type(2))) int int2_t;
typedef __attribute__((ext_vector_type(4))) int int4_t;
typedef __attribute__((ext_vector_type(4))) float float4_t;

static __device__ __forceinline__ unsigned short f2bf(float f) {
  unsigned u = __builtin_bit_cast(unsigned, f);
  u += 0x7FFFu + ((u >> 16) & 1u);
  return (unsigned short)(u >> 16);
}

static __device__ __forceinline__ unsigned cvt_pk(float lo, float hi) {
  unsigned r;
  asm("v_cvt_pk_bf16_f32 %0, %1, %2" : "=v"(r) : "v"(lo), "v"(hi));
  return r;
}

// Q/K fragment-order flat index (shorts) for 32x32x16 A/B frags:
// lane(l31,h) of tile t, k-half kh reads 8 contiguous shorts at
// ((t*2+kh)*64 + h*32 + l31)*8  ->  whole wave = 1KB contiguous.
static __device__ __forceinline__ int fqk(int n, int cr) {
  return ((n >> 5) * 2 + (cr >> 4)) * 512 + ((cr >> 3) & 1) * 256 +
         (n & 31) * 8 + (cr & 7);
}

// ---------------------------------------------------------------------------
// Kernel 0: one-time W pack f32 -> bf16. rows [0,32)=Wq, [32,64)=Wk, [64,320)=Wv
// ---------------------------------------------------------------------------
__global__ __launch_bounds__(64) void pack_w_kernel(
    const float* __restrict__ Wq, const float* __restrict__ Wk,
    const float* __restrict__ Wv, unsigned short* __restrict__ Wbf)
{
  const int row = blockIdx.x;
  const int t = threadIdx.x;
  const float* src = row < 32 ? Wq + (size_t)row * NC
                   : (row < 64 ? Wk + (size_t)(row - 32) * NC
                               : Wv + (size_t)(row - 64) * NC);
  float4_t v = *(const float4_t*)(src + t * 4);
  int2_t p;
  p[0] = cvt_pk(v[0], v[1]);
  p[1] = cvt_pk(v[2], v[3]);
  *(int2_t*)(Wbf + (size_t)row * NC + t * 4) = p;
}

// ---------------------------------------------------------------------------
// Kernel 1: QKV projection. BM=32, grid 512, 2 blocks/CU. x chunk staged in
// LDS bf16, XOR-swizzled. Swapped MFMA: D^T[m][d]. Outputs:
//   Qt/Kt in 32x32x16-frag order (fqk), Vt panel-major [n/16][c][16].
// ---------------------------------------------------------------------------
__global__ __launch_bounds__(256, 2) void qkv_kernel(
    const float* __restrict__ x, const unsigned short* __restrict__ Wbf,
    const float* __restrict__ bq, const float* __restrict__ bk,
    const float* __restrict__ bv,
    unsigned short* __restrict__ Qt, unsigned short* __restrict__ Kt,
    unsigned short* __restrict__ Vt)
{
  __shared__ unsigned short xT[2][32 * 64];

  const int bid = blockIdx.x;
  const int b   = bid >> 7;
  const int m0  = (bid & 127) * 32;
  const int tid = threadIdx.x;
  const int w    = tid >> 6;
  const int lane = tid & 63;
  const int lg   = lane >> 4;
  const int lm   = lane & 15;

  const int mcol = tid & 31, kg = tid >> 5;
  const float* xld = x + (size_t)b * NC * NN + (size_t)(kg * 8) * NN + m0 + mcol;
  const int wofs = mcol * 64 + ((kg ^ (mcol & 7)) << 3);
  const unsigned short* wrow = Wbf + (size_t)(w * 80 + lm) * NC;

  const f32x4 zero4 = {0.f, 0.f, 0.f, 0.f};
  f32x4 acc[5][2];
#pragma unroll
  for (int df = 0; df < 5; df++)
#pragma unroll
    for (int mf = 0; mf < 2; mf++) acc[df][mf] = zero4;

  float xg[8], xn[8];
#pragma unroll
  for (int j = 0; j < 8; j++) xg[j] = xld[(size_t)j * NN];

#define QCHUNK(C, XC, XN, BUF) {                                              \
    if ((C) < 3) {                                                            \
      _Pragma("unroll") for (int j = 0; j < 8; j++)                           \
        XN[j] = xld[(size_t)(((C) + 1) * 64 + j) * NN];                       \
    }                                                                         \
    int4_t xwv;                                                               \
    xwv[0] = cvt_pk(XC[0], XC[1]); xwv[1] = cvt_pk(XC[2], XC[3]);             \
    xwv[2] = cvt_pk(XC[4], XC[5]); xwv[3] = cvt_pk(XC[6], XC[7]);             \
    *(int4_t*)(&xT[BUF][wofs]) = xwv;                                         \
    __syncthreads();                                                          \
    _Pragma("unroll") for (int ks = 0; ks < 2; ks++) {                        \
      short8_t xf[2];                                                         \
      _Pragma("unroll") for (int mf = 0; mf < 2; mf++) {                      \
        const int row = mf * 16 + lm;                                         \
        const int unit = (ks * 4 + lg) ^ (lm & 7);                            \
        xf[mf] = *(const short8_t*)(&xT[BUF][row * 64 + unit * 8]);           \
      }                                                                       \
      _Pragma("unroll") for (int df = 0; df < 5; df++) {                      \
        const short8_t wf = *(const short8_t*)(wrow + (size_t)df * 16 * NC +  \
                                               (C) * 64 + ks * 32 + lg * 8);  \
        _Pragma("unroll") for (int mf = 0; mf < 2; mf++)                      \
          acc[df][mf] = __builtin_amdgcn_mfma_f32_16x16x32_bf16(              \
              xf[mf], wf, acc[df][mf], 0, 0, 0);                              \
      }                                                                       \
    }                                                                         \
  }

  QCHUNK(0, xg, xn, 0)
  QCHUNK(1, xn, xg, 1)
  QCHUNK(2, xg, xn, 0)
  QCHUNK(3, xn, xg, 1)
#undef QCHUNK

  // acc[df][mf][i] = D^T[m = m0+mf*16+4lg+i][d = w*80+df*16+lm]
#pragma unroll
  for (int df = 0; df < 5; df++) {
    const int dbase = w * 80 + df * 16;
    if (dbase < 64) {
      const bool isq = dbase < 32;
      const float bia = isq ? bq[dbase + lm] : bk[dbase - 32 + lm];
      unsigned short* dst = (isq ? Qt : Kt) + (size_t)b * NN * NCR;
      const int dcol = (isq ? dbase : dbase - 32) + lm;
#pragma unroll
      for (int mf = 0; mf < 2; mf++)
#pragma unroll
        for (int i = 0; i < 4; i++) {
          const int m = m0 + mf * 16 + lg * 4 + i;
          dst[fqk(m, dcol)] = f2bf(acc[df][mf][i] + bia);
        }
    } else {
      const int c = dbase - 64 + lm;
      const float bia = bv[c];
#pragma unroll
      for (int mf = 0; mf < 2; mf++) {
        int2_t p;
        p[0] = cvt_pk(acc[df][mf][0] + bia, acc[df][mf][1] + bia);
        p[1] = cvt_pk(acc[df][mf][2] + bia, acc[df][mf][3] + bia);
        // panel-major: ((n>>4)*256 + c)*16 + (n&15);  n = m0+mf*16+lg*4+i
        *(int2_t*)(Vt + (size_t)b * NN * NC +
                   (size_t)(((m0 >> 4) + mf) * 256 + c) * 16 + lg * 4) = p;
      }
    }
  }
}

// ---------------------------------------------------------------------------
// Kernel 2: barrier-free, LDS-free, register-pipelined attention.
// 32x32x16 swapped MFMAs. Iteration T: loads K(T+2),V(T+1); computes S(T+1)
// (MFMA+relu+cvt_pk+permlane -> pk regs); PV consumes pk(T),V(T) -- produced
// in PREVIOUS iterations, so PV has zero same-iteration dependencies.
// Wave = (m32, c64); block = 4 waves (m128); grid 512 = b(4) x cq(4) x mt(32),
// XCD-swizzled so each XCD's L2 holds 2 c-quarters of one batch.
// All global loads are contiguous 1KB wave-reads (frag-order Q/K, panel V).
// ---------------------------------------------------------------------------
__global__ __launch_bounds__(256, 2) void attn_kernel(
    const unsigned short* __restrict__ Qt, const unsigned short* __restrict__ Kt,
    const unsigned short* __restrict__ Vt, const float* __restrict__ x,
    const float* __restrict__ gamma, float* __restrict__ out)
{
  const int bid = blockIdx.x;
  const int xcd = bid & 7;
  const int idx = bid >> 3;
  const int b   = xcd >> 1;
  const int cq  = (xcd & 1) * 2 + (idx & 1);
  const int mt  = idx >> 1;
  const int tid = threadIdx.x;
  const int w    = tid >> 6;
  const int lane = tid & 63;
  const int l31  = lane & 31;
  const int h    = lane >> 5;

  const int m0w   = mt * 128 + w * 32;
  const int cbase = cq * 64;

  const unsigned short* Qfb = Qt + (size_t)b * NN * NCR;
  const unsigned short* Kl  = Kt + (size_t)b * NN * NCR + h * 256 + l31 * 8;
  const unsigned short* Vl  = Vt + (size_t)b * NN * NC +
                              (size_t)(cbase + l31) * 16 + h * 8;

  const short8_t qf0 = *(const short8_t*)(Qfb + ((m0w >> 5) * 2) * 512 + h * 256 + l31 * 8);
  const short8_t qf1 = *(const short8_t*)(Qfb + ((m0w >> 5) * 2 + 1) * 512 + h * 256 + l31 * 8);

  f32x16 accA, accB, zero16;
#pragma unroll
  for (int i = 0; i < 16; i++) { accA[i] = 0.f; accB[i] = 0.f; zero16[i] = 0.f; }
  float dsum = 0.f;

#define LOADK(DST, T) {                                                       \
    const int tt = (T) & 127;                                                 \
    DST[0] = *(const short8_t*)(Kl + tt * 1024);                              \
    DST[1] = *(const short8_t*)(Kl + tt * 1024 + 512);                        \
  }
#define LOADV(DST, T) {                                                       \
    const int pp = ((T) & 127) * 2;                                           \
    DST[0][0] = *(const short8_t*)(Vl + (size_t)pp * 4096);                   \
    DST[0][1] = *(const short8_t*)(Vl + (size_t)(pp + 1) * 4096);             \
    DST[1][0] = *(const short8_t*)(Vl + 512 + (size_t)pp * 4096);             \
    DST[1][1] = *(const short8_t*)(Vl + 512 + (size_t)(pp + 1) * 4096);       \
  }
// S for one 32-n tile -> packed P frags (R6 hardware-verified mapping)
#define SCOMP(KC, PK) {                                                       \
    f32x16 s = __builtin_amdgcn_mfma_f32_32x32x16_bf16(KC[0], qf0, zero16, 0, 0, 0); \
    s = __builtin_amdgcn_mfma_f32_32x32x16_bf16(KC[1], qf1, s, 0, 0, 0);      \
    float r_[16];                                                             \
    _Pragma("unroll") for (int i = 0; i < 16; i++) r_[i] = fmaxf(s[i], 0.f);  \
    dsum += (((r_[0] + r_[1]) + (r_[2] + r_[3])) +                            \
             ((r_[4] + r_[5]) + (r_[6] + r_[7]))) +                           \
            (((r_[8] + r_[9]) + (r_[10] + r_[11])) +                          \
             ((r_[12] + r_[13]) + (r_[14] + r_[15])));                        \
    unsigned p0 = cvt_pk(r_[0], r_[1]), p1 = cvt_pk(r_[2], r_[3]);            \
    unsigned p2 = cvt_pk(r_[4], r_[5]), p3 = cvt_pk(r_[6], r_[7]);            \
    unsigned p4 = cvt_pk(r_[8], r_[9]), p5 = cvt_pk(r_[10], r_[11]);          \
    unsigned p6 = cvt_pk(r_[12], r_[13]), p7 = cvt_pk(r_[14], r_[15]);        \
    asm("v_permlane32_swap_b32 %0, %1" : "+v"(p0), "+v"(p2));                 \
    asm("v_permlane32_swap_b32 %0, %1" : "+v"(p1), "+v"(p3));                 \
    asm("v_permlane32_swap_b32 %0, %1" : "+v"(p4), "+v"(p6));                 \
    asm("v_permlane32_swap_b32 %0, %1" : "+v"(p5), "+v"(p7));                 \
    int4_t pb0i = {(int)p0, (int)p1, (int)p2, (int)p3};                       \
    int4_t pb1i = {(int)p4, (int)p5, (int)p6, (int)p7};                       \
    PK[0] = __builtin_bit_cast(short8_t, pb0i);                               \
    PK[1] = __builtin_bit_cast(short8_t, pb1i);                               \
  }
// Pipelined iteration: PV(T) uses PKC/VC from earlier iters; SCOMP makes PKN.
#define ITER(T, KC, KN, VC, VN, PKC, PKN, DOS) {                              \
    LOADK(KN, (T) + 2)                                                        \
    LOADV(VN, (T) + 1)                                                        \
    if (DOS) { SCOMP(KC, PKN) }                                               \
    accA = __builtin_amdgcn_mfma_f32_32x32x16_bf16(VC[0][0], PKC[0], accA, 0, 0, 0); \
    accA = __builtin_amdgcn_mfma_f32_32x32x16_bf16(VC[0][1], PKC[1], accA, 0, 0, 0); \
    accB = __builtin_amdgcn_mfma_f32_32x32x16_bf16(VC[1][0], PKC[0], accB, 0, 0, 0); \
    accB = __builtin_amdgcn_mfma_f32_32x32x16_bf16(VC[1][1], PKC[1], accB, 0, 0, 0); \
  }

  short8_t kA[2], kB[2], vA[2][2], vB[2][2], pkA[2], pkB[2];
  // prologue: K(0)->kB (consumed now), K(1)->kA, V(0)->vA, pk(0)->pkA
  LOADK(kB, 0)
  LOADK(kA, 1)
  LOADV(vA, 0)
  SCOMP(kB, pkA)

#pragma unroll 1
  for (int t = 0; t < 126; t += 2) {
    ITER(t, kA, kB, vA, vB, pkA, pkB, true)
    ITER(t + 1, kB, kA, vB, vA, pkB, pkA, true)
  }
  ITER(126, kA, kB, vA, vB, pkA, pkB, true)
  ITER(127, kB, kA, vB, vA, pkB, pkA, false)   // no SCOMP: avoid double-count
#undef ITER
#undef SCOMP
#undef LOADV
#undef LOADK

  // denominator: lane (l31,h) holds rows == {4h..} pattern; fold h-halves
  dsum += __shfl_xor(dsum, 32);
  const float rden = 1.0f / (dsum > 1e-12f ? dsum : 1e-12f);
  const float g0 = gamma[0];

  const int m = m0w + l31;
  const float* xb = x + (size_t)b * NC * NN + m;
  float* ob = out + (size_t)b * NC * NN + m;
#pragma unroll
  for (int r = 0; r < 16; r++) {
    const int c0 = cbase + (r & 3) + 8 * (r >> 2) + 4 * h;
    ob[(size_t)c0 * NN] = g0 * accA[r] * rden + xb[(size_t)c0 * NN];
    const int c1 = c0 + 32;
    ob[(size_t)c1 * NN] = g0 * accB[r] * rden + xb[(size_t)c1 * NN];
  }
}

extern "C" void kernel_launch(void* const* d_in, const int* in_sizes, int n_in,
                              void* d_out, int out_size, void* d_ws, size_t ws_size,
                              hipStream_t stream) {
  const float* x     = (const float*)d_in[0];
  const float* Wq    = (const float*)d_in[1];
  const float* bq    = (const float*)d_in[2];
  const float* Wk    = (const float*)d_in[3];
  const float* bk    = (const float*)d_in[4];
  const float* Wv    = (const float*)d_in[5];
  const float* bv    = (const float*)d_in[6];
  const float* gamma = (const float*)d_in[7];
  float* out = (float*)d_out;

  // ws (bf16): Wbf[320][256], Qt[4][NN][32] frag-order, Kt same, Vt[4][NN/16][256][16]
  unsigned short* Wbf = (unsigned short*)d_ws;
  unsigned short* Qt  = Wbf + (size_t)320 * NC;
  unsigned short* Kt  = Qt + (size_t)NB * NN * NCR;
  unsigned short* Vt  = Kt + (size_t)NB * NN * NCR;

  hipLaunchKernelGGL(pack_w_kernel, dim3(320), dim3(64), 0, stream,
                     Wq, Wk, Wv, Wbf);
  hipLaunchKernelGGL(qkv_kernel, dim3(512), dim3(256), 0, stream,
                     x, Wbf, bq, bk, bv, Qt, Kt, Vt);
  hipLaunchKernelGGL(attn_kernel, dim3(512), dim3(256), 0, stream,
                     Qt, Kt, Vt, x, gamma, out);
}